// Round 1
// baseline (371.252 us; speedup 1.0000x reference)
//
#include <hip/hip_runtime.h>
#include <hip/hip_bf16.h>

// Problem constants
#define B_LON 15      // NLON
#define NW    32      // TYPE_OF_WINDOWS
#define NTOK  144     // N_TOK
#define DIM   192
#define NH    6
#define HD    32
#define K3    576     // 3*DIM
#define MROWS (B_LON*NW*NTOK)   // 69120
#define NN    (NTOK*NTOK)       // 20736
#define SCALE 0.17677669529663687f  // 32^-0.5

typedef __attribute__((ext_vector_type(8))) short bf16x8;
typedef __attribute__((ext_vector_type(8))) unsigned short u16x8;
typedef __attribute__((ext_vector_type(4))) float f32x4;

__device__ inline unsigned short f2bf(float f) {
  __bf16 h = (__bf16)f;
  return __builtin_bit_cast(unsigned short, h);
}
__device__ inline float bf2f(unsigned short u) {
  union { unsigned int i; float f; } c;
  c.i = ((unsigned int)u) << 16;
  return c.f;
}

// element-octet counts for the weight-convert kernel
#define NQ8 13824     // 576*192/8
#define NP8 4608      // 192*192/8

// ---------------------------------------------------------------------------
// Kernel -1: fp32 -> bf16 pre-convert of qkv_w, proj_w (x is now converted
// in-kernel by qkv_gemm_k's staging loop).
// ---------------------------------------------------------------------------
__global__ __launch_bounds__(256) void conv_bf_k(
    const float* __restrict__ qw, const float* __restrict__ pw,
    unsigned short* __restrict__ qwbf, unsigned short* __restrict__ pwbf) {
  const long gid = (long)blockIdx.x * 256 + threadIdx.x;
  const float* src;
  unsigned short* dst;
  long off;
  if (gid < NQ8) { src = qw; dst = qwbf; off = gid; }
  else           { src = pw; dst = pwbf; off = gid - NQ8; }
  const float4 a = ((const float4*)src)[off * 2];
  const float4 b = ((const float4*)src)[off * 2 + 1];
  u16x8 u = {f2bf(a.x), f2bf(a.y), f2bf(a.z), f2bf(a.w),
             f2bf(b.x), f2bf(b.y), f2bf(b.z), f2bf(b.w)};
  *(u16x8*)&dst[off * 8] = u;
}

// ---------------------------------------------------------------------------
// Kernel 0: bias precompute.  biasb[wh][ij] = bf16(btab[pos[ij]*192 + wh]).
// ---------------------------------------------------------------------------
__global__ __launch_bounds__(256) void bias_pre_k(
    const float* __restrict__ btab, const int* __restrict__ pos,
    unsigned short* __restrict__ biasb) {
  const int wh  = blockIdx.x;          // 0..191
  const int seg = blockIdx.y * 2304;   // 9 segs of 2304
  unsigned short* dst = biasb + (size_t)wh * NN;
#pragma unroll
  for (int it = 0; it < 9; ++it) {
    const int e = seg + it * 256 + threadIdx.x;
    dst[e] = f2bf(btab[(size_t)pos[e] * (NW * NH) + wh]);
  }
}

// ---------------------------------------------------------------------------
// Kernel 1: QKV GEMM v2 — A-stationary.
// Block = 128 rows x ALL 576 cols. A-tile (fp32 -> bf16) staged to LDS ONCE
// (single barrier per block, vs 9 in v1). W fragments are read directly from
// global per MFMA step: W is 221 KB bf16, permanently L2-hot, and the
// fragment read pattern (16 rows x 64 contiguous bytes) is fully
// line-utilized. X is fetched exactly once (v1 re-fetched it 9x).
// 4 waves; wave w owns rows [w*32, w*32+32); per n-chunk acc[2][4].
// ---------------------------------------------------------------------------
__global__ __launch_bounds__(256) void qkv_gemm_k(
    const float* __restrict__ X, const unsigned short* __restrict__ W,
    const float* __restrict__ Bv,
    unsigned short* __restrict__ qb, unsigned short* __restrict__ kb,
    unsigned short* __restrict__ vb) {
  __shared__ unsigned short As[128 * 200];   // stride 200: +8 elems -> 2-way (free)
  const int t    = threadIdx.x;
  const int m0   = blockIdx.x * 128;
  const int w    = t >> 6;
  const int lane = t & 63;
  const int ln15 = lane & 15;
  const int quad = lane >> 4;

  // stage A: 128 rows x 48 float4 each, fp32 -> bf16, coalesced
  for (int it = t; it < 128 * 48; it += 256) {
    const int row = it / 48;
    const int c4  = it % 48;
    const float4 a = *(const float4*)&X[(size_t)(m0 + row) * 192 + c4 * 4];
    ushort4 u = {f2bf(a.x), f2bf(a.y), f2bf(a.z), f2bf(a.w)};
    *(ushort4*)&As[row * 200 + c4 * 4] = u;
  }
  __syncthreads();

  for (int s = 0; s < 3; ++s) {
    const float sc2 = (s == 0) ? SCALE : 1.0f;
    unsigned short* dst = (s == 0) ? qb : (s == 1 ? kb : vb);
    for (int nc = 0; nc < 3; ++nc) {
      const int n0 = s * 192 + nc * 64;
      const int nr = nc * 64;

      f32x4 acc[2][4];
#pragma unroll
      for (int i = 0; i < 2; ++i)
#pragma unroll
        for (int j = 0; j < 4; ++j) acc[i][j] = (f32x4){0.f, 0.f, 0.f, 0.f};

#pragma unroll
      for (int k0 = 0; k0 < 192; k0 += 32) {
        bf16x8 af[2], bfr[4];
#pragma unroll
        for (int mt = 0; mt < 2; ++mt)
          af[mt] = *(bf16x8*)&As[(w * 32 + mt * 16 + ln15) * 200 + k0 + quad * 8];
#pragma unroll
        for (int nt = 0; nt < 4; ++nt)
          bfr[nt] = *(const bf16x8*)&W[(size_t)(n0 + nt * 16 + ln15) * 192 + k0 + quad * 8];
#pragma unroll
        for (int mt = 0; mt < 2; ++mt)
#pragma unroll
          for (int nt = 0; nt < 4; ++nt)
            acc[mt][nt] = __builtin_amdgcn_mfma_f32_16x16x32_bf16(
                af[mt], bfr[nt], acc[mt][nt], 0, 0, 0);
      }

#pragma unroll
      for (int nt = 0; nt < 4; ++nt) {
        const int colg = n0 + nt * 16 + ln15;
        const int h    = (nr + nt * 16 + ln15) >> 5;
        const int dd   = (nr + nt * 16 + ln15) & 31;
        const float bias = Bv[colg];
#pragma unroll
        for (int mt = 0; mt < 2; ++mt) {
#pragma unroll
          for (int r = 0; r < 4; ++r) {
            const int m  = m0 + w * 32 + mt * 16 + quad * 4 + r;
            const int bw = m / NTOK;
            const int n  = m % NTOK;
            const unsigned short val = f2bf((acc[mt][nt][r] + bias) * sc2);
            if (s < 2)
              dst[((size_t)(bw * NH + h) * NTOK + n) * HD + dd] = val;   // [bw,h,n,d]
            else
              dst[((size_t)(bw * NH + h) * HD + dd) * NTOK + n] = val;   // [bw,h,d,n]
          }
        }
      }
    }
  }
}

// ---------------------------------------------------------------------------
// Kernel 2: MFMA attention, LDS-resident K/V (unchanged).
// ---------------------------------------------------------------------------
__global__ __launch_bounds__(192, 3) void attn_k(
    const unsigned short* __restrict__ qbuf, const unsigned short* __restrict__ kbuf,
    const unsigned short* __restrict__ vbuf, const float* __restrict__ mask,
    const unsigned short* __restrict__ biasb, unsigned short* __restrict__ ao) {
  __shared__ unsigned short Ks[NTOK * 36];     // K  [144][32] @ stride 36
  __shared__ unsigned short Vs[32 * 160];      // V^T [32][144] @ stride 160, cols 144..159 zero
  __shared__ unsigned short Ps[3 * 16 * 168];  // per-wave P

  const int t    = threadIdx.x;
  const int wave = t / 64;
  const int lane = t & 63;
  const int ln15 = lane & 15;
  const int quad = lane >> 4;
  const int idx  = blockIdx.x;
  const int h    = idx / 480;
  const int bw   = idx % 480;
  const int w    = bw & 31;
  const int wh   = w * NH + h;
  const size_t hb = (size_t)(bw * NH + h) * (NTOK * HD);
  const unsigned short* qh = qbuf + hb;
  const float* maskp = mask + (size_t)bw * NN;
  const unsigned short* biasp = biasb + (size_t)wh * NN;
  unsigned short* ps = &Ps[wave * 16 * 168];

  // stage K: 144 rows x 4 u16x8
  for (int it = t; it < 576; it += 192) {
    const int row = it >> 2;
    const int col = (it & 3) * 8;
    *(u16x8*)&Ks[row * 36 + col] = *(const u16x8*)&kbuf[hb + row * HD + col];
  }
  // stage V^T: 32 rows x 18 u16x8
  for (int it = t; it < 576; it += 192) {
    const int row = it / 18;
    const int col = (it % 18) * 8;
    *(u16x8*)&Vs[row * 160 + col] = *(const u16x8*)&vbuf[hb + row * NTOK + col];
  }
  // zero V pad cols 144..159
  if (t < 64) {
    u16x8 z = {0, 0, 0, 0, 0, 0, 0, 0};
    *(u16x8*)&Vs[(t >> 1) * 160 + 144 + (t & 1) * 8] = z;
  }
  // zero P pad cols 144..159 (per wave)
  {
    ushort4 z = {0, 0, 0, 0};
    *(ushort4*)&ps[(lane >> 2) * 168 + 144 + (lane & 3) * 4] = z;
  }
  __syncthreads();

  for (int g = wave * 3; g < wave * 3 + 3; ++g) {
    const int i0 = g * 16;
    const int ib = i0 + quad * 4;

    // S = Q K^T  (A-frag from global, B-frags from LDS)
    const bf16x8 qf = *(const bf16x8*)&qh[(i0 + ln15) * HD + quad * 8];
    f32x4 s[9];
#pragma unroll
    for (int jt = 0; jt < 9; ++jt) {
      const bf16x8 kf = *(const bf16x8*)&Ks[(jt * 16 + ln15) * 36 + quad * 8];
      s[jt] = (f32x4){0.f, 0.f, 0.f, 0.f};
      s[jt] = __builtin_amdgcn_mfma_f32_16x16x32_bf16(qf, kf, s[jt], 0, 0, 0);
    }

    // + bias + mask (streamed, independent loads)
#pragma unroll
    for (int jt = 0; jt < 9; ++jt) {
      const int j = jt * 16 + ln15;
#pragma unroll
      for (int r = 0; r < 4; ++r) {
        const int ij = (ib + r) * NTOK + j;
        s[jt][r] += bf2f(biasp[ij]) + maskp[ij];
      }
    }

    // softmax over j (row = ib+r lives in the 16-lane ln15 group)
    float rinv[4];
#pragma unroll
    for (int r = 0; r < 4; ++r) {
      float mx = s[0][r];
#pragma unroll
      for (int jt = 1; jt < 9; ++jt) mx = fmaxf(mx, s[jt][r]);
#pragma unroll
      for (int off = 1; off < 16; off <<= 1) mx = fmaxf(mx, __shfl_xor(mx, off));
      float sum = 0.f;
#pragma unroll
      for (int jt = 0; jt < 9; ++jt) {
        const float e = __expf(s[jt][r] - mx);
        s[jt][r] = e;
        sum += e;
      }
#pragma unroll
      for (int off = 1; off < 16; off <<= 1) sum += __shfl_xor(sum, off);
      rinv[r] = 1.0f / sum;
    }

    // P: C-layout -> LDS -> A-layout (wave-internal)
#pragma unroll
    for (int jt = 0; jt < 9; ++jt)
#pragma unroll
      for (int r = 0; r < 4; ++r)
        ps[(quad * 4 + r) * 168 + jt * 16 + ln15] = f2bf(s[jt][r]);

    // O = P V  (K padded to 160; P and V pads both zeroed)
    f32x4 o[2] = {{0.f, 0.f, 0.f, 0.f}, {0.f, 0.f, 0.f, 0.f}};
#pragma unroll
    for (int kt = 0; kt < 5; ++kt) {
      const bf16x8 pf = *(const bf16x8*)&ps[ln15 * 168 + kt * 32 + quad * 8];
#pragma unroll
      for (int nt = 0; nt < 2; ++nt) {
        const bf16x8 vf = *(const bf16x8*)&Vs[(nt * 16 + ln15) * 160 + kt * 32 + quad * 8];
        o[nt] = __builtin_amdgcn_mfma_f32_16x16x32_bf16(pf, vf, o[nt], 0, 0, 0);
      }
    }

    // store O (bf16) into [m=bw*144+i][c=h*32+d]
#pragma unroll
    for (int nt = 0; nt < 2; ++nt)
#pragma unroll
      for (int r = 0; r < 4; ++r)
        ao[(size_t)(bw * NTOK + ib + r) * DIM + h * HD + nt * 16 + ln15] =
            f2bf(o[nt][r] * rinv[r]);
  }
}

// ---------------------------------------------------------------------------
// Kernel 3: proj GEMM v2 — A-stationary, same structure as qkv v2.
// Block = 128 rows x all 192 cols; AO staged once; W from global (L2-hot).
// ---------------------------------------------------------------------------
__global__ __launch_bounds__(256) void proj_gemm_k(
    const unsigned short* __restrict__ AO, const unsigned short* __restrict__ W,
    const float* __restrict__ Bv, float* __restrict__ out) {
  __shared__ unsigned short As[128 * 200];
  const int t    = threadIdx.x;
  const int m0   = blockIdx.x * 128;
  const int w    = t >> 6;
  const int lane = t & 63;
  const int ln15 = lane & 15;
  const int quad = lane >> 4;

  // stage A: 128 rows x 24 u16x8 each, coalesced
  for (int it = t; it < 128 * 24; it += 256) {
    const int row = it / 24;
    const int c8  = it % 24;
    *(u16x8*)&As[row * 200 + c8 * 8] =
        *(const u16x8*)&AO[(size_t)(m0 + row) * 192 + c8 * 8];
  }
  __syncthreads();

  for (int nc = 0; nc < 3; ++nc) {
    const int n0 = nc * 64;

    f32x4 acc[2][4];
#pragma unroll
    for (int i = 0; i < 2; ++i)
#pragma unroll
      for (int j = 0; j < 4; ++j) acc[i][j] = (f32x4){0.f, 0.f, 0.f, 0.f};

#pragma unroll
    for (int k0 = 0; k0 < 192; k0 += 32) {
      bf16x8 af[2], bfr[4];
#pragma unroll
      for (int mt = 0; mt < 2; ++mt)
        af[mt] = *(bf16x8*)&As[(w * 32 + mt * 16 + ln15) * 200 + k0 + quad * 8];
#pragma unroll
      for (int nt = 0; nt < 4; ++nt)
        bfr[nt] = *(const bf16x8*)&W[(size_t)(n0 + nt * 16 + ln15) * 192 + k0 + quad * 8];
#pragma unroll
      for (int mt = 0; mt < 2; ++mt)
#pragma unroll
        for (int nt = 0; nt < 4; ++nt)
          acc[mt][nt] = __builtin_amdgcn_mfma_f32_16x16x32_bf16(
              af[mt], bfr[nt], acc[mt][nt], 0, 0, 0);
    }

#pragma unroll
    for (int nt = 0; nt < 4; ++nt) {
      const int colg = n0 + nt * 16 + ln15;
      const float bias = Bv[colg];
#pragma unroll
      for (int mt = 0; mt < 2; ++mt) {
#pragma unroll
        for (int r = 0; r < 4; ++r) {
          const int m = m0 + w * 32 + mt * 16 + quad * 4 + r;
          out[(size_t)m * 192 + colg] = acc[mt][nt][r] + bias;
        }
      }
    }
  }
}

// ---------------------------------------------------------------------------
extern "C" void kernel_launch(void* const* d_in, const int* in_sizes, int n_in,
                              void* d_out, int out_size, void* d_ws, size_t ws_size,
                              hipStream_t stream) {
  const float* x      = (const float*)d_in[0];
  const float* mask   = (const float*)d_in[1];
  const float* qkv_w  = (const float*)d_in[2];
  const float* qkv_b  = (const float*)d_in[3];
  const float* proj_w = (const float*)d_in[4];
  const float* proj_b = (const float*)d_in[5];
  const float* btab   = (const float*)d_in[6];
  const int*   pos    = (const int*)d_in[7];
  float* out = (float*)d_out;

  unsigned short* ws = (unsigned short*)d_ws;
  const size_t sz = (size_t)MROWS * DIM;   // 13,271,040 elements
  unsigned short* qbuf  = ws;
  unsigned short* kbuf  = ws + sz;
  unsigned short* vbuf  = ws + 2 * sz;
  unsigned short* aobuf = ws + 3 * sz + 256;
  unsigned short* biasb = ws + 4 * sz + 1024;           // 192*20736 bf16 = 8 MB
  unsigned short* qwbf  = biasb + (size_t)192 * NN;
  unsigned short* pwbf  = qwbf + (size_t)K3 * DIM;

  conv_bf_k<<<(NQ8 + NP8) / 256, 256, 0, stream>>>(qkv_w, proj_w, qwbf, pwbf);
  bias_pre_k<<<dim3(NW * NH, 9), 256, 0, stream>>>(btab, pos, biasb);
  qkv_gemm_k<<<MROWS / 128, 256, 0, stream>>>(
      x, qwbf, qkv_b, qbuf, kbuf, vbuf);
  attn_k<<<NH * 480, 192, 0, stream>>>(
      qbuf, kbuf, vbuf, mask, biasb, aobuf);
  proj_gemm_k<<<MROWS / 128, 256, 0, stream>>>(
      aobuf, pwbf, proj_b, out);
}

// Round 2
// 318.054 us; speedup vs baseline: 1.1673x; 1.1673x over previous
//
#include <hip/hip_runtime.h>
#include <hip/hip_bf16.h>

// Problem constants
#define B_LON 15      // NLON
#define NW    32      // TYPE_OF_WINDOWS
#define NTOK  144     // N_TOK
#define DIM   192
#define NH    6
#define HD    32
#define K3    576     // 3*DIM
#define MROWS (B_LON*NW*NTOK)   // 69120
#define NN    (NTOK*NTOK)       // 20736
#define SCALE 0.17677669529663687f  // 32^-0.5

typedef __attribute__((ext_vector_type(8))) short bf16x8;
typedef __attribute__((ext_vector_type(8))) unsigned short u16x8;
typedef __attribute__((ext_vector_type(4))) float f32x4;

__device__ inline unsigned short f2bf(float f) {
  __bf16 h = (__bf16)f;
  return __builtin_bit_cast(unsigned short, h);
}
__device__ inline float bf2f(unsigned short u) {
  union { unsigned int i; float f; } c;
  c.i = ((unsigned int)u) << 16;
  return c.f;
}

// element-octet counts for the convert kernel
#define NX8 1658880   // 69120*192/8
#define NQ8 13824     // 576*192/8
#define NP8 4608      // 192*192/8

// ---------------------------------------------------------------------------
// Kernel -1: fp32 -> bf16 pre-convert of x, qkv_w, proj_w.
// ---------------------------------------------------------------------------
__global__ __launch_bounds__(256) void conv_bf_k(
    const float* __restrict__ x, const float* __restrict__ qw,
    const float* __restrict__ pw,
    unsigned short* __restrict__ xbf, unsigned short* __restrict__ qwbf,
    unsigned short* __restrict__ pwbf) {
  const long gid = (long)blockIdx.x * 256 + threadIdx.x;
  const float* src;
  unsigned short* dst;
  long off;
  if (gid < NX8)            { src = x;  dst = xbf;  off = gid; }
  else if (gid < NX8 + NQ8) { src = qw; dst = qwbf; off = gid - NX8; }
  else                      { src = pw; dst = pwbf; off = gid - NX8 - NQ8; }
  const float4 a = ((const float4*)src)[off * 2];
  const float4 b = ((const float4*)src)[off * 2 + 1];
  u16x8 u = {f2bf(a.x), f2bf(a.y), f2bf(a.z), f2bf(a.w),
             f2bf(b.x), f2bf(b.y), f2bf(b.z), f2bf(b.w)};
  *(u16x8*)&dst[off * 8] = u;
}

// ---------------------------------------------------------------------------
// Kernel 0: bias precompute.  biasb[wh][ij] = bf16(btab[pos[ij]*192 + wh]).
// ---------------------------------------------------------------------------
__global__ __launch_bounds__(256) void bias_pre_k(
    const float* __restrict__ btab, const int* __restrict__ pos,
    unsigned short* __restrict__ biasb) {
  const int wh  = blockIdx.x;          // 0..191
  const int seg = blockIdx.y * 2304;   // 9 segs of 2304
  unsigned short* dst = biasb + (size_t)wh * NN;
#pragma unroll
  for (int it = 0; it < 9; ++it) {
    const int e = seg + it * 256 + threadIdx.x;
    dst[e] = f2bf(btab[(size_t)pos[e] * (NW * NH) + wh]);
  }
}

// ---------------------------------------------------------------------------
// Kernel 1: QKV GEMM v3 — single-barrier full-K tiles.
// Block = 64 rows x 64 cols; K=192 staged ENTIRELY in LDS (both operands),
// so there is exactly one __syncthreads per block and zero global loads in
// the MFMA loop (v1 paid 9 barrier-drains/block; v2 paid global-latency with
// a starved grid). Grid (9, 1080) = 9720 blocks, 51.2 KB LDS -> 3 blocks/CU
// and the grid fills them. Staging reads are fully contiguous per tile.
// 4 waves; wave w owns rows [w*16, w*16+16); acc[4] over 4 col-tiles.
// ---------------------------------------------------------------------------
__global__ __launch_bounds__(256) void qkv_gemm_k(
    const unsigned short* __restrict__ X, const unsigned short* __restrict__ W,
    const float* __restrict__ Bv,
    unsigned short* __restrict__ qb, unsigned short* __restrict__ kb,
    unsigned short* __restrict__ vb) {
  __shared__ unsigned short As[64 * 200];
  __shared__ unsigned short Bs[64 * 200];
  const int t    = threadIdx.x;
  const int n0   = blockIdx.x * 64;
  const int m0   = blockIdx.y * 64;
  const int w    = t >> 6;
  const int lane = t & 63;
  const int ln15 = lane & 15;
  const int quad = lane >> 4;

  // stage A: 64 rows x 24 u16x8 (contiguous 24.6 KB region of X)
#pragma unroll
  for (int it = t; it < 1536; it += 256) {
    const int row = it / 24;
    const int c8  = (it % 24) * 8;
    *(u16x8*)&As[row * 200 + c8] = *(const u16x8*)&X[(size_t)(m0 + row) * 192 + c8];
  }
  // stage B: 64 rows of W (L2-hot)
#pragma unroll
  for (int it = t; it < 1536; it += 256) {
    const int row = it / 24;
    const int c8  = (it % 24) * 8;
    *(u16x8*)&Bs[row * 200 + c8] = *(const u16x8*)&W[(size_t)(n0 + row) * 192 + c8];
  }
  __syncthreads();

  f32x4 acc[4];
#pragma unroll
  for (int j = 0; j < 4; ++j) acc[j] = (f32x4){0.f, 0.f, 0.f, 0.f};

#pragma unroll
  for (int k0 = 0; k0 < 192; k0 += 32) {
    const bf16x8 af = *(bf16x8*)&As[(w * 16 + ln15) * 200 + k0 + quad * 8];
#pragma unroll
    for (int nt = 0; nt < 4; ++nt) {
      const bf16x8 bfr = *(bf16x8*)&Bs[(nt * 16 + ln15) * 200 + k0 + quad * 8];
      acc[nt] = __builtin_amdgcn_mfma_f32_16x16x32_bf16(af, bfr, acc[nt], 0, 0, 0);
    }
  }

  const int s   = n0 / 192;
  const int nr  = n0 % 192;
  const float sc2 = (s == 0) ? SCALE : 1.0f;
  unsigned short* dst = (s == 0) ? qb : (s == 1 ? kb : vb);
#pragma unroll
  for (int nt = 0; nt < 4; ++nt) {
    const int colg = n0 + nt * 16 + ln15;
    const int h    = (nr + nt * 16 + ln15) >> 5;
    const int dd   = (nr + nt * 16 + ln15) & 31;
    const float bias = Bv[colg];
#pragma unroll
    for (int r = 0; r < 4; ++r) {
      const int m  = m0 + w * 16 + quad * 4 + r;
      const int bw = m / NTOK;
      const int n  = m % NTOK;
      const unsigned short val = f2bf((acc[nt][r] + bias) * sc2);
      if (s < 2)
        dst[((size_t)(bw * NH + h) * NTOK + n) * HD + dd] = val;   // [bw,h,n,d]
      else
        dst[((size_t)(bw * NH + h) * HD + dd) * NTOK + n] = val;   // [bw,h,d,n]
    }
  }
}

// ---------------------------------------------------------------------------
// Kernel 2: MFMA attention, LDS-resident K/V (unchanged).
// ---------------------------------------------------------------------------
__global__ __launch_bounds__(192, 3) void attn_k(
    const unsigned short* __restrict__ qbuf, const unsigned short* __restrict__ kbuf,
    const unsigned short* __restrict__ vbuf, const float* __restrict__ mask,
    const unsigned short* __restrict__ biasb, unsigned short* __restrict__ ao) {
  __shared__ unsigned short Ks[NTOK * 36];     // K  [144][32] @ stride 36
  __shared__ unsigned short Vs[32 * 160];      // V^T [32][144] @ stride 160, cols 144..159 zero
  __shared__ unsigned short Ps[3 * 16 * 168];  // per-wave P

  const int t    = threadIdx.x;
  const int wave = t / 64;
  const int lane = t & 63;
  const int ln15 = lane & 15;
  const int quad = lane >> 4;
  const int idx  = blockIdx.x;
  const int h    = idx / 480;
  const int bw   = idx % 480;
  const int w    = bw & 31;
  const int wh   = w * NH + h;
  const size_t hb = (size_t)(bw * NH + h) * (NTOK * HD);
  const unsigned short* qh = qbuf + hb;
  const float* maskp = mask + (size_t)bw * NN;
  const unsigned short* biasp = biasb + (size_t)wh * NN;
  unsigned short* ps = &Ps[wave * 16 * 168];

  // stage K: 144 rows x 4 u16x8
  for (int it = t; it < 576; it += 192) {
    const int row = it >> 2;
    const int col = (it & 3) * 8;
    *(u16x8*)&Ks[row * 36 + col] = *(const u16x8*)&kbuf[hb + row * HD + col];
  }
  // stage V^T: 32 rows x 18 u16x8
  for (int it = t; it < 576; it += 192) {
    const int row = it / 18;
    const int col = (it % 18) * 8;
    *(u16x8*)&Vs[row * 160 + col] = *(const u16x8*)&vbuf[hb + row * NTOK + col];
  }
  // zero V pad cols 144..159
  if (t < 64) {
    u16x8 z = {0, 0, 0, 0, 0, 0, 0, 0};
    *(u16x8*)&Vs[(t >> 1) * 160 + 144 + (t & 1) * 8] = z;
  }
  // zero P pad cols 144..159 (per wave)
  {
    ushort4 z = {0, 0, 0, 0};
    *(ushort4*)&ps[(lane >> 2) * 168 + 144 + (lane & 3) * 4] = z;
  }
  __syncthreads();

  for (int g = wave * 3; g < wave * 3 + 3; ++g) {
    const int i0 = g * 16;
    const int ib = i0 + quad * 4;

    // S = Q K^T  (A-frag from global, B-frags from LDS)
    const bf16x8 qf = *(const bf16x8*)&qh[(i0 + ln15) * HD + quad * 8];
    f32x4 s[9];
#pragma unroll
    for (int jt = 0; jt < 9; ++jt) {
      const bf16x8 kf = *(const bf16x8*)&Ks[(jt * 16 + ln15) * 36 + quad * 8];
      s[jt] = (f32x4){0.f, 0.f, 0.f, 0.f};
      s[jt] = __builtin_amdgcn_mfma_f32_16x16x32_bf16(qf, kf, s[jt], 0, 0, 0);
    }

    // + bias + mask (streamed, independent loads)
#pragma unroll
    for (int jt = 0; jt < 9; ++jt) {
      const int j = jt * 16 + ln15;
#pragma unroll
      for (int r = 0; r < 4; ++r) {
        const int ij = (ib + r) * NTOK + j;
        s[jt][r] += bf2f(biasp[ij]) + maskp[ij];
      }
    }

    // softmax over j (row = ib+r lives in the 16-lane ln15 group)
    float rinv[4];
#pragma unroll
    for (int r = 0; r < 4; ++r) {
      float mx = s[0][r];
#pragma unroll
      for (int jt = 1; jt < 9; ++jt) mx = fmaxf(mx, s[jt][r]);
#pragma unroll
      for (int off = 1; off < 16; off <<= 1) mx = fmaxf(mx, __shfl_xor(mx, off));
      float sum = 0.f;
#pragma unroll
      for (int jt = 0; jt < 9; ++jt) {
        const float e = __expf(s[jt][r] - mx);
        s[jt][r] = e;
        sum += e;
      }
#pragma unroll
      for (int off = 1; off < 16; off <<= 1) sum += __shfl_xor(sum, off);
      rinv[r] = 1.0f / sum;
    }

    // P: C-layout -> LDS -> A-layout (wave-internal)
#pragma unroll
    for (int jt = 0; jt < 9; ++jt)
#pragma unroll
      for (int r = 0; r < 4; ++r)
        ps[(quad * 4 + r) * 168 + jt * 16 + ln15] = f2bf(s[jt][r]);

    // O = P V  (K padded to 160; P and V pads both zeroed)
    f32x4 o[2] = {{0.f, 0.f, 0.f, 0.f}, {0.f, 0.f, 0.f, 0.f}};
#pragma unroll
    for (int kt = 0; kt < 5; ++kt) {
      const bf16x8 pf = *(const bf16x8*)&ps[ln15 * 168 + kt * 32 + quad * 8];
#pragma unroll
      for (int nt = 0; nt < 2; ++nt) {
        const bf16x8 vf = *(const bf16x8*)&Vs[(nt * 16 + ln15) * 160 + kt * 32 + quad * 8];
        o[nt] = __builtin_amdgcn_mfma_f32_16x16x32_bf16(pf, vf, o[nt], 0, 0, 0);
      }
    }

    // store O (bf16) into [m=bw*144+i][c=h*32+d]
#pragma unroll
    for (int nt = 0; nt < 2; ++nt)
#pragma unroll
      for (int r = 0; r < 4; ++r)
        ao[(size_t)(bw * NTOK + ib + r) * DIM + h * HD + nt * 16 + ln15] =
            f2bf(o[nt][r] * rinv[r]);
  }
}

// ---------------------------------------------------------------------------
// Kernel 3: proj GEMM v3 — single-barrier full-K tiles (same as qkv v3).
// ---------------------------------------------------------------------------
__global__ __launch_bounds__(256) void proj_gemm_k(
    const unsigned short* __restrict__ AO, const unsigned short* __restrict__ W,
    const float* __restrict__ Bv, float* __restrict__ out) {
  __shared__ unsigned short As[64 * 200];
  __shared__ unsigned short Bs[64 * 200];
  const int t    = threadIdx.x;
  const int n0   = blockIdx.x * 64;
  const int m0   = blockIdx.y * 64;
  const int w    = t >> 6;
  const int lane = t & 63;
  const int ln15 = lane & 15;
  const int quad = lane >> 4;

#pragma unroll
  for (int it = t; it < 1536; it += 256) {
    const int row = it / 24;
    const int c8  = (it % 24) * 8;
    *(u16x8*)&As[row * 200 + c8] = *(const u16x8*)&AO[(size_t)(m0 + row) * 192 + c8];
  }
#pragma unroll
  for (int it = t; it < 1536; it += 256) {
    const int row = it / 24;
    const int c8  = (it % 24) * 8;
    *(u16x8*)&Bs[row * 200 + c8] = *(const u16x8*)&W[(size_t)(n0 + row) * 192 + c8];
  }
  __syncthreads();

  f32x4 acc[4];
#pragma unroll
  for (int j = 0; j < 4; ++j) acc[j] = (f32x4){0.f, 0.f, 0.f, 0.f};

#pragma unroll
  for (int k0 = 0; k0 < 192; k0 += 32) {
    const bf16x8 af = *(bf16x8*)&As[(w * 16 + ln15) * 200 + k0 + quad * 8];
#pragma unroll
    for (int nt = 0; nt < 4; ++nt) {
      const bf16x8 bfr = *(bf16x8*)&Bs[(nt * 16 + ln15) * 200 + k0 + quad * 8];
      acc[nt] = __builtin_amdgcn_mfma_f32_16x16x32_bf16(af, bfr, acc[nt], 0, 0, 0);
    }
  }

#pragma unroll
  for (int nt = 0; nt < 4; ++nt) {
    const int colg = n0 + nt * 16 + ln15;
    const float bias = Bv[colg];
#pragma unroll
    for (int r = 0; r < 4; ++r) {
      const int m = m0 + w * 16 + quad * 4 + r;
      out[(size_t)m * 192 + colg] = acc[nt][r] + bias;
    }
  }
}

// ---------------------------------------------------------------------------
extern "C" void kernel_launch(void* const* d_in, const int* in_sizes, int n_in,
                              void* d_out, int out_size, void* d_ws, size_t ws_size,
                              hipStream_t stream) {
  const float* x      = (const float*)d_in[0];
  const float* mask   = (const float*)d_in[1];
  const float* qkv_w  = (const float*)d_in[2];
  const float* qkv_b  = (const float*)d_in[3];
  const float* proj_w = (const float*)d_in[4];
  const float* proj_b = (const float*)d_in[5];
  const float* btab   = (const float*)d_in[6];
  const int*   pos    = (const int*)d_in[7];
  float* out = (float*)d_out;

  unsigned short* ws = (unsigned short*)d_ws;
  const size_t sz = (size_t)MROWS * DIM;   // 13,271,040 elements
  unsigned short* qbuf  = ws;
  unsigned short* kbuf  = ws + sz;
  unsigned short* vbuf  = ws + 2 * sz;
  unsigned short* aobuf = ws + 3 * sz + 256;
  unsigned short* biasb = ws + 4 * sz + 1024;           // 192*20736 bf16 = 8 MB
  unsigned short* xbf   = biasb + (size_t)192 * NN;
  unsigned short* qwbf  = xbf + sz;
  unsigned short* pwbf  = qwbf + (size_t)K3 * DIM;

  conv_bf_k<<<NX8 / 256 + NQ8 / 256 + NP8 / 256, 256, 0, stream>>>(
      x, qkv_w, proj_w, xbf, qwbf, pwbf);
  bias_pre_k<<<dim3(NW * NH, 9), 256, 0, stream>>>(btab, pos, biasb);
  qkv_gemm_k<<<dim3(K3 / 64, MROWS / 64), 256, 0, stream>>>(
      xbf, qwbf, qkv_b, qbuf, kbuf, vbuf);
  attn_k<<<NH * 480, 192, 0, stream>>>(
      qbuf, kbuf, vbuf, mask, biasb, aobuf);
  proj_gemm_k<<<dim3(DIM / 64, MROWS / 64), 256, 0, stream>>>(
      aobuf, pwbf, proj_b, out);
}

// Round 3
// 290.782 us; speedup vs baseline: 1.2767x; 1.0938x over previous
//
#include <hip/hip_runtime.h>
#include <hip/hip_bf16.h>

// Problem constants
#define B_LON 15      // NLON
#define NW    32      // TYPE_OF_WINDOWS
#define NTOK  144     // N_TOK
#define DIM   192
#define NH    6
#define HD    32
#define K3    576     // 3*DIM
#define MROWS (B_LON*NW*NTOK)   // 69120
#define NN    (NTOK*NTOK)       // 20736
#define SCALE 0.17677669529663687f  // 32^-0.5

typedef __attribute__((ext_vector_type(8))) short bf16x8;
typedef __attribute__((ext_vector_type(8))) unsigned short u16x8;
typedef __attribute__((ext_vector_type(4))) float f32x4;

__device__ inline unsigned short f2bf(float f) {
  __bf16 h = (__bf16)f;
  return __builtin_bit_cast(unsigned short, h);
}
__device__ inline float bf2f(unsigned short u) {
  union { unsigned int i; float f; } c;
  c.i = ((unsigned int)u) << 16;
  return c.f;
}

// element-octet counts for the convert kernel
#define NX8 1658880   // 69120*192/8
#define NQ8 13824     // 576*192/8
#define NP8 4608      // 192*192/8

// ---------------------------------------------------------------------------
// Kernel -1: fp32 -> bf16 pre-convert of x, qkv_w, proj_w.
// ---------------------------------------------------------------------------
__global__ __launch_bounds__(256) void conv_bf_k(
    const float* __restrict__ x, const float* __restrict__ qw,
    const float* __restrict__ pw,
    unsigned short* __restrict__ xbf, unsigned short* __restrict__ qwbf,
    unsigned short* __restrict__ pwbf) {
  const long gid = (long)blockIdx.x * 256 + threadIdx.x;
  const float* src;
  unsigned short* dst;
  long off;
  if (gid < NX8)            { src = x;  dst = xbf;  off = gid; }
  else if (gid < NX8 + NQ8) { src = qw; dst = qwbf; off = gid - NX8; }
  else                      { src = pw; dst = pwbf; off = gid - NX8 - NQ8; }
  const float4 a = ((const float4*)src)[off * 2];
  const float4 b = ((const float4*)src)[off * 2 + 1];
  u16x8 u = {f2bf(a.x), f2bf(a.y), f2bf(a.z), f2bf(a.w),
             f2bf(b.x), f2bf(b.y), f2bf(b.z), f2bf(b.w)};
  *(u16x8*)&dst[off * 8] = u;
}

// ---------------------------------------------------------------------------
// Kernel 0: bias precompute.  biasb[wh][ij] = bf16(btab[pos[ij]*192 + wh]).
// ---------------------------------------------------------------------------
__global__ __launch_bounds__(256) void bias_pre_k(
    const float* __restrict__ btab, const int* __restrict__ pos,
    unsigned short* __restrict__ biasb) {
  const int wh  = blockIdx.x;          // 0..191
  const int seg = blockIdx.y * 2304;   // 9 segs of 2304
  unsigned short* dst = biasb + (size_t)wh * NN;
#pragma unroll
  for (int it = 0; it < 9; ++it) {
    const int e = seg + it * 256 + threadIdx.x;
    dst[e] = f2bf(btab[(size_t)pos[e] * (NW * NH) + wh]);
  }
}

// ---------------------------------------------------------------------------
// Kernel 1+2 FUSED: per-(bw,h) QKV-slice GEMM -> LDS -> attention.
// Eliminates the q/k/v global buffers (79.6 MB write + 79.6 MB read).
// Phase 1: GEMM 144x96 (K=192). A-frags from global X-bf16 (L2/L3-hot,
//   26.5 MB), B-frags from global W (221 KB, permanently L2-resident).
//   Per wave: 3 m-tiles x 6 n-tiles x 6 k-steps = 108 MFMAs with full ILP;
//   9 waves/CU (3 blocks x 3 waves, 47 KB LDS) hide the L2 latency
//   (unlike R1's 2-blocks/CU starvation).
//   Epilogue writes Q,K (row-major [tok][d]) and V^T ([d][tok]) straight
//   into LDS in the layouts attention needs -- the scattered-2B global V^T
//   store from the old qkv kernel disappears.
// Phase 2: identical to previous attn_k, except Q fragments come from LDS.
// ---------------------------------------------------------------------------
__global__ __launch_bounds__(192, 3) void fused_attn_k(
    const unsigned short* __restrict__ X, const unsigned short* __restrict__ W,
    const float* __restrict__ Bv, const float* __restrict__ mask,
    const unsigned short* __restrict__ biasb, unsigned short* __restrict__ ao) {
  __shared__ unsigned short Qs[NTOK * 36];     // Q  [144][32] @ stride 36
  __shared__ unsigned short Ks[NTOK * 36];     // K  [144][32] @ stride 36
  __shared__ unsigned short Vs[32 * 160];      // V^T [32][144] @ stride 160, cols 144..159 zero
  __shared__ unsigned short Ps[3 * 16 * 168];  // per-wave P

  const int t    = threadIdx.x;
  const int wave = t / 64;
  const int lane = t & 63;
  const int ln15 = lane & 15;
  const int quad = lane >> 4;
  const int idx  = blockIdx.x;
  const int h    = idx / 480;
  const int bw   = idx % 480;
  const int w    = bw & 31;
  const int wh   = w * NH + h;
  const float* maskp = mask + (size_t)bw * NN;
  const unsigned short* biasp = biasb + (size_t)wh * NN;
  unsigned short* ps = &Ps[wave * 16 * 168];
  const int wv3 = wave * 3;

  // zero V pad cols 144..159
  if (t < 64) {
    u16x8 z = {0, 0, 0, 0, 0, 0, 0, 0};
    *(u16x8*)&Vs[(t >> 1) * 160 + 144 + (t & 1) * 8] = z;
  }
  // zero P pad cols 144..159 (per wave)
  {
    ushort4 z = {0, 0, 0, 0};
    *(ushort4*)&ps[(lane >> 2) * 168 + 144 + (lane & 3) * 4] = z;
  }

  // ---- phase 1: QKV GEMM for this (bw, h): 144 rows x 96 cols, K=192 ----
  f32x4 acc[3][6];
#pragma unroll
  for (int mt = 0; mt < 3; ++mt)
#pragma unroll
    for (int nt = 0; nt < 6; ++nt) acc[mt][nt] = (f32x4){0.f, 0.f, 0.f, 0.f};

#pragma unroll
  for (int kk = 0; kk < 6; ++kk) {
    const int k0 = kk * 32 + quad * 8;
    bf16x8 af[3], bfr[6];
#pragma unroll
    for (int mt = 0; mt < 3; ++mt)
      af[mt] = *(const bf16x8*)&X[(size_t)(bw * NTOK + (wv3 + mt) * 16 + ln15) * DIM + k0];
#pragma unroll
    for (int nt = 0; nt < 6; ++nt) {
      const int wrow = (nt >> 1) * DIM + h * HD + (nt & 1) * 16 + ln15;
      bfr[nt] = *(const bf16x8*)&W[(size_t)wrow * DIM + k0];
    }
#pragma unroll
    for (int mt = 0; mt < 3; ++mt)
#pragma unroll
      for (int nt = 0; nt < 6; ++nt)
        acc[mt][nt] = __builtin_amdgcn_mfma_f32_16x16x32_bf16(
            af[mt], bfr[nt], acc[mt][nt], 0, 0, 0);
  }

  // epilogue: +bias (and scale for Q), straight into LDS
#pragma unroll
  for (int nt = 0; nt < 6; ++nt) {
    const int dd   = (nt & 1) * 16 + ln15;            // 0..31 within head
    const float bias = Bv[(nt >> 1) * DIM + h * HD + dd];
#pragma unroll
    for (int mt = 0; mt < 3; ++mt) {
      const int tok = (wv3 + mt) * 16 + quad * 4;
#pragma unroll
      for (int r = 0; r < 4; ++r) {
        const float v = acc[mt][nt][r] + bias;
        if (nt < 2)      Qs[(tok + r) * 36 + dd] = f2bf(v * SCALE);
        else if (nt < 4) Ks[(tok + r) * 36 + dd] = f2bf(v);
        else             Vs[dd * 160 + tok + r]  = f2bf(v);
      }
    }
  }
  __syncthreads();

  // ---- phase 2: attention (unchanged; Q-frags now from LDS) ----
  for (int g = wv3; g < wv3 + 3; ++g) {
    const int i0 = g * 16;
    const int ib = i0 + quad * 4;

    // S = Q K^T
    const bf16x8 qf = *(const bf16x8*)&Qs[(i0 + ln15) * 36 + quad * 8];
    f32x4 s[9];
#pragma unroll
    for (int jt = 0; jt < 9; ++jt) {
      const bf16x8 kf = *(const bf16x8*)&Ks[(jt * 16 + ln15) * 36 + quad * 8];
      s[jt] = (f32x4){0.f, 0.f, 0.f, 0.f};
      s[jt] = __builtin_amdgcn_mfma_f32_16x16x32_bf16(qf, kf, s[jt], 0, 0, 0);
    }

    // + bias + mask (streamed, independent loads)
#pragma unroll
    for (int jt = 0; jt < 9; ++jt) {
      const int j = jt * 16 + ln15;
#pragma unroll
      for (int r = 0; r < 4; ++r) {
        const int ij = (ib + r) * NTOK + j;
        s[jt][r] += bf2f(biasp[ij]) + maskp[ij];
      }
    }

    // softmax over j (row = ib+r lives in the 16-lane ln15 group)
    float rinv[4];
#pragma unroll
    for (int r = 0; r < 4; ++r) {
      float mx = s[0][r];
#pragma unroll
      for (int jt = 1; jt < 9; ++jt) mx = fmaxf(mx, s[jt][r]);
#pragma unroll
      for (int off = 1; off < 16; off <<= 1) mx = fmaxf(mx, __shfl_xor(mx, off));
      float sum = 0.f;
#pragma unroll
      for (int jt = 0; jt < 9; ++jt) {
        const float e = __expf(s[jt][r] - mx);
        s[jt][r] = e;
        sum += e;
      }
#pragma unroll
      for (int off = 1; off < 16; off <<= 1) sum += __shfl_xor(sum, off);
      rinv[r] = 1.0f / sum;
    }

    // P: C-layout -> LDS -> A-layout (wave-internal)
#pragma unroll
    for (int jt = 0; jt < 9; ++jt)
#pragma unroll
      for (int r = 0; r < 4; ++r)
        ps[(quad * 4 + r) * 168 + jt * 16 + ln15] = f2bf(s[jt][r]);

    // O = P V  (K padded to 160; P and V pads both zeroed)
    f32x4 o[2] = {{0.f, 0.f, 0.f, 0.f}, {0.f, 0.f, 0.f, 0.f}};
#pragma unroll
    for (int kt = 0; kt < 5; ++kt) {
      const bf16x8 pf = *(const bf16x8*)&ps[ln15 * 168 + kt * 32 + quad * 8];
#pragma unroll
      for (int nt = 0; nt < 2; ++nt) {
        const bf16x8 vf = *(const bf16x8*)&Vs[(nt * 16 + ln15) * 160 + kt * 32 + quad * 8];
        o[nt] = __builtin_amdgcn_mfma_f32_16x16x32_bf16(pf, vf, o[nt], 0, 0, 0);
      }
    }

    // store O (bf16) into [m=bw*144+i][c=h*32+d]
#pragma unroll
    for (int nt = 0; nt < 2; ++nt)
#pragma unroll
      for (int r = 0; r < 4; ++r)
        ao[(size_t)(bw * NTOK + ib + r) * DIM + h * HD + nt * 16 + ln15] =
            f2bf(o[nt][r] * rinv[r]);
  }
}

// ---------------------------------------------------------------------------
// Kernel 3: proj GEMM — single-barrier full-K tiles (unchanged from R2).
// ---------------------------------------------------------------------------
__global__ __launch_bounds__(256) void proj_gemm_k(
    const unsigned short* __restrict__ AO, const unsigned short* __restrict__ W,
    const float* __restrict__ Bv, float* __restrict__ out) {
  __shared__ unsigned short As[64 * 200];
  __shared__ unsigned short Bs[64 * 200];
  const int t    = threadIdx.x;
  const int n0   = blockIdx.x * 64;
  const int m0   = blockIdx.y * 64;
  const int w    = t >> 6;
  const int lane = t & 63;
  const int ln15 = lane & 15;
  const int quad = lane >> 4;

#pragma unroll
  for (int it = t; it < 1536; it += 256) {
    const int row = it / 24;
    const int c8  = (it % 24) * 8;
    *(u16x8*)&As[row * 200 + c8] = *(const u16x8*)&AO[(size_t)(m0 + row) * 192 + c8];
  }
#pragma unroll
  for (int it = t; it < 1536; it += 256) {
    const int row = it / 24;
    const int c8  = (it % 24) * 8;
    *(u16x8*)&Bs[row * 200 + c8] = *(const u16x8*)&W[(size_t)(n0 + row) * 192 + c8];
  }
  __syncthreads();

  f32x4 acc[4];
#pragma unroll
  for (int j = 0; j < 4; ++j) acc[j] = (f32x4){0.f, 0.f, 0.f, 0.f};

#pragma unroll
  for (int k0 = 0; k0 < 192; k0 += 32) {
    const bf16x8 af = *(bf16x8*)&As[(w * 16 + ln15) * 200 + k0 + quad * 8];
#pragma unroll
    for (int nt = 0; nt < 4; ++nt) {
      const bf16x8 bfr = *(bf16x8*)&Bs[(nt * 16 + ln15) * 200 + k0 + quad * 8];
      acc[nt] = __builtin_amdgcn_mfma_f32_16x16x32_bf16(af, bfr, acc[nt], 0, 0, 0);
    }
  }

#pragma unroll
  for (int nt = 0; nt < 4; ++nt) {
    const int colg = n0 + nt * 16 + ln15;
    const float bias = Bv[colg];
#pragma unroll
    for (int r = 0; r < 4; ++r) {
      const int m = m0 + w * 16 + quad * 4 + r;
      out[(size_t)m * 192 + colg] = acc[nt][r] + bias;
    }
  }
}

// ---------------------------------------------------------------------------
extern "C" void kernel_launch(void* const* d_in, const int* in_sizes, int n_in,
                              void* d_out, int out_size, void* d_ws, size_t ws_size,
                              hipStream_t stream) {
  const float* x      = (const float*)d_in[0];
  const float* mask   = (const float*)d_in[1];
  const float* qkv_w  = (const float*)d_in[2];
  const float* qkv_b  = (const float*)d_in[3];
  const float* proj_w = (const float*)d_in[4];
  const float* proj_b = (const float*)d_in[5];
  const float* btab   = (const float*)d_in[6];
  const int*   pos    = (const int*)d_in[7];
  float* out = (float*)d_out;

  unsigned short* ws = (unsigned short*)d_ws;
  const size_t sz = (size_t)MROWS * DIM;   // 13,271,040 elements
  unsigned short* aobuf = ws;
  unsigned short* biasb = ws + sz + 256;                // 192*20736 bf16 = 8 MB
  unsigned short* xbf   = biasb + (size_t)192 * NN + 256;
  unsigned short* qwbf  = xbf + sz;
  unsigned short* pwbf  = qwbf + (size_t)K3 * DIM;

  conv_bf_k<<<NX8 / 256 + NQ8 / 256 + NP8 / 256, 256, 0, stream>>>(
      x, qkv_w, proj_w, xbf, qwbf, pwbf);
  bias_pre_k<<<dim3(NW * NH, 9), 256, 0, stream>>>(btab, pos, biasb);
  fused_attn_k<<<NH * 480, 192, 0, stream>>>(
      xbf, qwbf, qkv_b, mask, biasb, aobuf);
  proj_gemm_k<<<dim3(DIM / 64, MROWS / 64), 256, 0, stream>>>(
      aobuf, pwbf, proj_b, out);
}

// Round 4
// 281.566 us; speedup vs baseline: 1.3185x; 1.0327x over previous
//
#include <hip/hip_runtime.h>
#include <hip/hip_bf16.h>

// Problem constants
#define B_LON 15      // NLON
#define NW    32      // TYPE_OF_WINDOWS
#define NTOK  144     // N_TOK
#define DIM   192
#define NH    6
#define HD    32
#define K3    576     // 3*DIM
#define MROWS (B_LON*NW*NTOK)   // 69120
#define NN    (NTOK*NTOK)       // 20736
#define SCALE 0.17677669529663687f  // 32^-0.5

typedef __attribute__((ext_vector_type(8))) short bf16x8;
typedef __attribute__((ext_vector_type(8))) unsigned short u16x8;
typedef __attribute__((ext_vector_type(4))) float f32x4;

__device__ inline unsigned short f2bf(float f) {
  __bf16 h = (__bf16)f;
  return __builtin_bit_cast(unsigned short, h);
}
__device__ inline float bf2f(unsigned short u) {
  union { unsigned int i; float f; } c;
  c.i = ((unsigned int)u) << 16;
  return c.f;
}

// element-octet counts for the convert kernel
#define NX8 1658880   // 69120*192/8
#define NQ8 13824     // 576*192/8
#define NP8 4608      // 192*192/8

// ---------------------------------------------------------------------------
// Kernel -1: fp32 -> bf16 pre-convert of x, qkv_w, proj_w.
// ---------------------------------------------------------------------------
__global__ __launch_bounds__(256) void conv_bf_k(
    const float* __restrict__ x, const float* __restrict__ qw,
    const float* __restrict__ pw,
    unsigned short* __restrict__ xbf, unsigned short* __restrict__ qwbf,
    unsigned short* __restrict__ pwbf) {
  const long gid = (long)blockIdx.x * 256 + threadIdx.x;
  const float* src;
  unsigned short* dst;
  long off;
  if (gid < NX8)            { src = x;  dst = xbf;  off = gid; }
  else if (gid < NX8 + NQ8) { src = qw; dst = qwbf; off = gid - NX8; }
  else                      { src = pw; dst = pwbf; off = gid - NX8 - NQ8; }
  const float4 a = ((const float4*)src)[off * 2];
  const float4 b = ((const float4*)src)[off * 2 + 1];
  u16x8 u = {f2bf(a.x), f2bf(a.y), f2bf(a.z), f2bf(a.w),
             f2bf(b.x), f2bf(b.y), f2bf(b.z), f2bf(b.w)};
  *(u16x8*)&dst[off * 8] = u;
}

// ---------------------------------------------------------------------------
// Kernel 0: bias precompute.  biasb[wh][ij] = bf16(btab[pos[ij]*192 + wh]).
// ---------------------------------------------------------------------------
__global__ __launch_bounds__(256) void bias_pre_k(
    const float* __restrict__ btab, const int* __restrict__ pos,
    unsigned short* __restrict__ biasb) {
  const int wh  = blockIdx.x;          // 0..191
  const int seg = blockIdx.y * 2304;   // 9 segs of 2304
  unsigned short* dst = biasb + (size_t)wh * NN;
#pragma unroll
  for (int it = 0; it < 9; ++it) {
    const int e = seg + it * 256 + threadIdx.x;
    dst[e] = f2bf(btab[(size_t)pos[e] * (NW * NH) + wh]);
  }
}

// ---------------------------------------------------------------------------
// Kernel 1+2 FUSED: per-(bw,h) QKV-slice GEMM -> LDS -> attention.
// v5: blockIdx remap for TEMPORAL L2 locality. R3's mapping put blocks
// sharing mask[bw] / X-rows on the same XCD (spacing 480 = 0 mod 8) but 480
// dispatch-slots apart -> per-XCD working set 60 masks = 5 MB > 4 MB L2 ->
// all 6 h-passes re-fetched everything (FETCH 213 MB vs ~100 MB working
// set). New mapping: xcd = idx&7, j = idx>>3, h = j%6, bw = (j/6)*8+xcd.
// The 6 h-blocks of one bw are same-XCD AND adjacent in dispatch order, so
// mask (83 KB) and X rows (55 KB) are fetched once and reused 5x from L2
// (concurrent per-XCD set ~16 bw x 124 KB = 2 MB < 4 MB). bias[wh] reuse
// across b (spacing 24 slots, ~96-slot window) gets partial L2 reuse.
// ---------------------------------------------------------------------------
__global__ __launch_bounds__(192, 3) void fused_attn_k(
    const unsigned short* __restrict__ X, const unsigned short* __restrict__ W,
    const float* __restrict__ Bv, const float* __restrict__ mask,
    const unsigned short* __restrict__ biasb, unsigned short* __restrict__ ao) {
  __shared__ unsigned short Qs[NTOK * 36];     // Q  [144][32] @ stride 36
  __shared__ unsigned short Ks[NTOK * 36];     // K  [144][32] @ stride 36
  __shared__ unsigned short Vs[32 * 160];      // V^T [32][144] @ stride 160, cols 144..159 zero
  __shared__ unsigned short Ps[3 * 16 * 168];  // per-wave P

  const int t    = threadIdx.x;
  const int wave = t / 64;
  const int lane = t & 63;
  const int ln15 = lane & 15;
  const int quad = lane >> 4;
  const int idx  = blockIdx.x;
  const int xcd  = idx & 7;
  const int j0   = idx >> 3;
  const int h    = j0 % 6;
  const int bw   = (j0 / 6) * 8 + xcd;
  const int w    = bw & 31;
  const int wh   = w * NH + h;
  const float* maskp = mask + (size_t)bw * NN;
  const unsigned short* biasp = biasb + (size_t)wh * NN;
  unsigned short* ps = &Ps[wave * 16 * 168];
  const int wv3 = wave * 3;

  // zero V pad cols 144..159
  if (t < 64) {
    u16x8 z = {0, 0, 0, 0, 0, 0, 0, 0};
    *(u16x8*)&Vs[(t >> 1) * 160 + 144 + (t & 1) * 8] = z;
  }
  // zero P pad cols 144..159 (per wave)
  {
    ushort4 z = {0, 0, 0, 0};
    *(ushort4*)&ps[(lane >> 2) * 168 + 144 + (lane & 3) * 4] = z;
  }

  // ---- phase 1: QKV GEMM for this (bw, h): 144 rows x 96 cols, K=192 ----
  f32x4 acc[3][6];
#pragma unroll
  for (int mt = 0; mt < 3; ++mt)
#pragma unroll
    for (int nt = 0; nt < 6; ++nt) acc[mt][nt] = (f32x4){0.f, 0.f, 0.f, 0.f};

#pragma unroll
  for (int kk = 0; kk < 6; ++kk) {
    const int k0 = kk * 32 + quad * 8;
    bf16x8 af[3], bfr[6];
#pragma unroll
    for (int mt = 0; mt < 3; ++mt)
      af[mt] = *(const bf16x8*)&X[(size_t)(bw * NTOK + (wv3 + mt) * 16 + ln15) * DIM + k0];
#pragma unroll
    for (int nt = 0; nt < 6; ++nt) {
      const int wrow = (nt >> 1) * DIM + h * HD + (nt & 1) * 16 + ln15;
      bfr[nt] = *(const bf16x8*)&W[(size_t)wrow * DIM + k0];
    }
#pragma unroll
    for (int mt = 0; mt < 3; ++mt)
#pragma unroll
      for (int nt = 0; nt < 6; ++nt)
        acc[mt][nt] = __builtin_amdgcn_mfma_f32_16x16x32_bf16(
            af[mt], bfr[nt], acc[mt][nt], 0, 0, 0);
  }

  // epilogue: +bias (and scale for Q), straight into LDS
#pragma unroll
  for (int nt = 0; nt < 6; ++nt) {
    const int dd   = (nt & 1) * 16 + ln15;            // 0..31 within head
    const float bias = Bv[(nt >> 1) * DIM + h * HD + dd];
#pragma unroll
    for (int mt = 0; mt < 3; ++mt) {
      const int tok = (wv3 + mt) * 16 + quad * 4;
#pragma unroll
      for (int r = 0; r < 4; ++r) {
        const float v = acc[mt][nt][r] + bias;
        if (nt < 2)      Qs[(tok + r) * 36 + dd] = f2bf(v * SCALE);
        else if (nt < 4) Ks[(tok + r) * 36 + dd] = f2bf(v);
        else             Vs[dd * 160 + tok + r]  = f2bf(v);
      }
    }
  }
  __syncthreads();

  // ---- phase 2: attention ----
  for (int g = wv3; g < wv3 + 3; ++g) {
    const int i0 = g * 16;
    const int ib = i0 + quad * 4;

    // S = Q K^T
    const bf16x8 qf = *(const bf16x8*)&Qs[(i0 + ln15) * 36 + quad * 8];
    f32x4 s[9];
#pragma unroll
    for (int jt = 0; jt < 9; ++jt) {
      const bf16x8 kf = *(const bf16x8*)&Ks[(jt * 16 + ln15) * 36 + quad * 8];
      s[jt] = (f32x4){0.f, 0.f, 0.f, 0.f};
      s[jt] = __builtin_amdgcn_mfma_f32_16x16x32_bf16(qf, kf, s[jt], 0, 0, 0);
    }

    // + bias + mask (streamed, independent loads)
#pragma unroll
    for (int jt = 0; jt < 9; ++jt) {
      const int j = jt * 16 + ln15;
#pragma unroll
      for (int r = 0; r < 4; ++r) {
        const int ij = (ib + r) * NTOK + j;
        s[jt][r] += bf2f(biasp[ij]) + maskp[ij];
      }
    }

    // softmax over j (row = ib+r lives in the 16-lane ln15 group)
    float rinv[4];
#pragma unroll
    for (int r = 0; r < 4; ++r) {
      float mx = s[0][r];
#pragma unroll
      for (int jt = 1; jt < 9; ++jt) mx = fmaxf(mx, s[jt][r]);
#pragma unroll
      for (int off = 1; off < 16; off <<= 1) mx = fmaxf(mx, __shfl_xor(mx, off));
      float sum = 0.f;
#pragma unroll
      for (int jt = 0; jt < 9; ++jt) {
        const float e = __expf(s[jt][r] - mx);
        s[jt][r] = e;
        sum += e;
      }
#pragma unroll
      for (int off = 1; off < 16; off <<= 1) sum += __shfl_xor(sum, off);
      rinv[r] = 1.0f / sum;
    }

    // P: C-layout -> LDS -> A-layout (wave-internal)
#pragma unroll
    for (int jt = 0; jt < 9; ++jt)
#pragma unroll
      for (int r = 0; r < 4; ++r)
        ps[(quad * 4 + r) * 168 + jt * 16 + ln15] = f2bf(s[jt][r]);

    // O = P V  (K padded to 160; P and V pads both zeroed)
    f32x4 o[2] = {{0.f, 0.f, 0.f, 0.f}, {0.f, 0.f, 0.f, 0.f}};
#pragma unroll
    for (int kt = 0; kt < 5; ++kt) {
      const bf16x8 pf = *(const bf16x8*)&ps[ln15 * 168 + kt * 32 + quad * 8];
#pragma unroll
      for (int nt = 0; nt < 2; ++nt) {
        const bf16x8 vf = *(const bf16x8*)&Vs[(nt * 16 + ln15) * 160 + kt * 32 + quad * 8];
        o[nt] = __builtin_amdgcn_mfma_f32_16x16x32_bf16(pf, vf, o[nt], 0, 0, 0);
      }
    }

    // store O (bf16) into [m=bw*144+i][c=h*32+d]
#pragma unroll
    for (int nt = 0; nt < 2; ++nt)
#pragma unroll
      for (int r = 0; r < 4; ++r)
        ao[(size_t)(bw * NTOK + ib + r) * DIM + h * HD + nt * 16 + ln15] =
            f2bf(o[nt][r] * rinv[r]);
  }
}

// ---------------------------------------------------------------------------
// Kernel 3: proj GEMM v4 — M=128 x N=64 full-K single-barrier tiles.
// A staged once for 2x the outputs of the R2 64x64 tile (9.3 vs 18 staged
// bytes/output). LDS 76.8 KB -> 2 blocks/CU; grid (3, 540) = 1620 blocks.
// 4 waves; wave w owns rows [w*32, w*32+32); acc[2][4].
// ---------------------------------------------------------------------------
__global__ __launch_bounds__(256) void proj_gemm_k(
    const unsigned short* __restrict__ AO, const unsigned short* __restrict__ W,
    const float* __restrict__ Bv, float* __restrict__ out) {
  __shared__ unsigned short As[128 * 200];
  __shared__ unsigned short Bs[64 * 200];
  const int t    = threadIdx.x;
  const int n0   = blockIdx.x * 64;
  const int m0   = blockIdx.y * 128;
  const int w    = t >> 6;
  const int lane = t & 63;
  const int ln15 = lane & 15;
  const int quad = lane >> 4;

  // stage A: 128 rows x 24 u16x8 (contiguous region of AO)
#pragma unroll
  for (int it = t; it < 3072; it += 256) {
    const int row = it / 24;
    const int c8  = (it % 24) * 8;
    *(u16x8*)&As[row * 200 + c8] = *(const u16x8*)&AO[(size_t)(m0 + row) * 192 + c8];
  }
  // stage B: 64 rows of W (L2-hot)
#pragma unroll
  for (int it = t; it < 1536; it += 256) {
    const int row = it / 24;
    const int c8  = (it % 24) * 8;
    *(u16x8*)&Bs[row * 200 + c8] = *(const u16x8*)&W[(size_t)(n0 + row) * 192 + c8];
  }
  __syncthreads();

  f32x4 acc[2][4];
#pragma unroll
  for (int i = 0; i < 2; ++i)
#pragma unroll
    for (int jj = 0; jj < 4; ++jj) acc[i][jj] = (f32x4){0.f, 0.f, 0.f, 0.f};

#pragma unroll
  for (int k0 = 0; k0 < 192; k0 += 32) {
    bf16x8 af[2], bfr[4];
#pragma unroll
    for (int mt = 0; mt < 2; ++mt)
      af[mt] = *(bf16x8*)&As[(w * 32 + mt * 16 + ln15) * 200 + k0 + quad * 8];
#pragma unroll
    for (int nt = 0; nt < 4; ++nt)
      bfr[nt] = *(bf16x8*)&Bs[(nt * 16 + ln15) * 200 + k0 + quad * 8];
#pragma unroll
    for (int mt = 0; mt < 2; ++mt)
#pragma unroll
      for (int nt = 0; nt < 4; ++nt)
        acc[mt][nt] = __builtin_amdgcn_mfma_f32_16x16x32_bf16(
            af[mt], bfr[nt], acc[mt][nt], 0, 0, 0);
  }

#pragma unroll
  for (int nt = 0; nt < 4; ++nt) {
    const int colg = n0 + nt * 16 + ln15;
    const float bias = Bv[colg];
#pragma unroll
    for (int mt = 0; mt < 2; ++mt) {
#pragma unroll
      for (int r = 0; r < 4; ++r) {
        const int m = m0 + w * 32 + mt * 16 + quad * 4 + r;
        out[(size_t)m * 192 + colg] = acc[mt][nt][r] + bias;
      }
    }
  }
}

// ---------------------------------------------------------------------------
extern "C" void kernel_launch(void* const* d_in, const int* in_sizes, int n_in,
                              void* d_out, int out_size, void* d_ws, size_t ws_size,
                              hipStream_t stream) {
  const float* x      = (const float*)d_in[0];
  const float* mask   = (const float*)d_in[1];
  const float* qkv_w  = (const float*)d_in[2];
  const float* qkv_b  = (const float*)d_in[3];
  const float* proj_w = (const float*)d_in[4];
  const float* proj_b = (const float*)d_in[5];
  const float* btab   = (const float*)d_in[6];
  const int*   pos    = (const int*)d_in[7];
  float* out = (float*)d_out;

  unsigned short* ws = (unsigned short*)d_ws;
  const size_t sz = (size_t)MROWS * DIM;   // 13,271,040 elements
  unsigned short* aobuf = ws;
  unsigned short* biasb = ws + sz + 256;                // 192*20736 bf16 = 8 MB
  unsigned short* xbf   = biasb + (size_t)192 * NN + 256;
  unsigned short* qwbf  = xbf + sz;
  unsigned short* pwbf  = qwbf + (size_t)K3 * DIM;

  conv_bf_k<<<NX8 / 256 + NQ8 / 256 + NP8 / 256, 256, 0, stream>>>(
      x, qkv_w, proj_w, xbf, qwbf, pwbf);
  bias_pre_k<<<dim3(NW * NH, 9), 256, 0, stream>>>(btab, pos, biasb);
  fused_attn_k<<<NH * 480, 192, 0, stream>>>(
      xbf, qwbf, qkv_b, mask, biasb, aobuf);
  proj_gemm_k<<<dim3(DIM / 64, MROWS / 128), 256, 0, stream>>>(
      aobuf, pwbf, proj_b, out);
}